// Round 11
// baseline (192.527 us; speedup 1.0000x reference)
//
#include <hip/hip_runtime.h>

#define Hh 240
#define Ww 304
#define IN_CH 16
#define OUT_CH 32
#define Bb 8
#define N_PER 65536
#define N_EV (Bb * N_PER)      // 524288 = 2^19 (event idx fits 19 bits)
#define CIN (IN_CH + 2)        // 18
#define NSEG (Bb * Hh * Ww)    // 583680 = 570 * 1024
#define NBLK 570               // scan blocks of 1024 elems

// fused conv tiling
#define TW 32
#define TH 8
#define HW_ 34                 // TW + 2 halo
#define HH_ 10                 // TH + 2 halo
#define HALO_PIX (HH_ * HW_)   // 340
#define NXT_TILES 10           // ceil(304/32)
#define NYT_TILES 30           // 240/8
#define OPITCH 33              // out repack pitch (f32)

typedef __attribute__((ext_vector_type(8))) short bf16x8;
typedef __attribute__((ext_vector_type(4))) float f32x4;

__device__ __forceinline__ unsigned short f2bf(float x) {
  unsigned u = __float_as_uint(x);
  unsigned r = u + 0x7fffu + ((u >> 16) & 1u);  // RNE
  return (unsigned short)(r >> 16);
}
__device__ __forceinline__ float bf2f(unsigned short b) {
  return __uint_as_float(((unsigned)b) << 16);
}
__device__ __forceinline__ unsigned pk2(float a, float b) {
  return (unsigned)f2bf(a) | ((unsigned)f2bf(b) << 16);
}

// ---- A: histogram + rank per event; key+rank packed as int2 ----------------
__global__ __launch_bounds__(256) void hist_rank_kernel(
    const float* __restrict__ events, const int* __restrict__ offsets,
    int* __restrict__ hist, int2* __restrict__ kr) {
  int i = blockIdx.x * blockDim.x + threadIdx.x;
  float4 ev = ((const float4*)events)[i];
  int yi = (int)rintf(ev.y * (float)Hh);
  yi = min(max(yi, 0), Hh - 1);
  int xi = (int)rintf(ev.x * (float)Ww);
  xi = min(max(xi, 0), Ww - 1);
  int b = 0;
#pragma unroll
  for (int j = 0; j < Bb; j++) b += (offsets[j] <= i) ? 1 : 0;
  int key = (b * Hh + yi) * Ww + xi;
  int pol = (ev.w != 0.0f) ? 1 : 0;
  int rank = atomicAdd(&hist[key], 1);
  kr[i] = make_int2(key | (pol << 31), rank);
}

// ---- S1: per-1024-block exclusive scan IN PLACE + block totals -------------
__global__ __launch_bounds__(256) void scan1_kernel(int* __restrict__ data,
                                                    int* __restrict__ blockSum) {
  __shared__ int lds[256];
  int b = blockIdx.x, t = threadIdx.x;
  int idx = b * 1024 + t * 4;
  int4 v = *(const int4*)(data + idx);
  int s0 = v.x, s1 = s0 + v.y, s2 = s1 + v.z, s3 = s2 + v.w;
  lds[t] = s3;
  __syncthreads();
  int val = s3;
  for (int off = 1; off < 256; off <<= 1) {
    int n = (t >= off) ? lds[t - off] : 0;
    __syncthreads();
    val += n;
    lds[t] = val;
    __syncthreads();
  }
  int excl = val - s3;
  int4 o;
  o.x = excl; o.y = excl + s0; o.z = excl + s1; o.w = excl + s2;
  *(int4*)(data + idx) = o;
  if (t == 255) blockSum[b] = val;
}

// ---- S2 + W merged: block 0 scans 570 totals; block 1 packs weights --------
// wprep [ky][n][64]: kl<54 -> kx=kl/18, ci=kl%18; kl>=54 zero (CIN stride).
__global__ __launch_bounds__(1024) void scan2_weights_kernel(
    const int* __restrict__ blockSum, int* __restrict__ blockOffset,
    const float* __restrict__ weight, unsigned short* __restrict__ wprep) {
  int t = threadIdx.x;
  if (blockIdx.x == 1) {
#pragma unroll
    for (int it = 0; it < 6; it++) {
      int idx = it * 1024 + t;              // < 3*32*64 = 6144
      int ky = idx >> 11;
      int rem = idx & 2047;
      int n = rem >> 6;
      int kl = rem & 63;
      unsigned short v = 0;
      if (kl < 54) {
        int kx = kl / 18, ci = kl - kx * 18;
        v = f2bf(weight[((ky * 3 + kx) * CIN + ci) * OUT_CH + n]);
      }
      wprep[idx] = v;
    }
    return;
  }
  __shared__ int lds[1024];
  int v = (t < NBLK) ? blockSum[t] : 0;
  lds[t] = v;
  __syncthreads();
  int val = v;
  for (int off = 1; off < 1024; off <<= 1) {
    int n = (t >= off) ? lds[t - off] : 0;
    __syncthreads();
    val += n;
    lds[t] = val;
    __syncthreads();
  }
  if (t < NBLK) blockOffset[t] = val - v;
  if (t == 0) blockOffset[NBLK] = lds[1023];  // = N_EV
}

// ---- B: scatter features (bf16, 32B) + meta into sorted order --------------
// sortedMeta[pos] = ev_idx(19b) | x(9b)<<19 | pol<<31 — stage 4 recovers the
// output pixel arithmetically; stage 1 reads pol from bit 31.
__global__ __launch_bounds__(256) void scatter_feat_kernel(
    const float* __restrict__ features, const int2* __restrict__ kr,
    const int* __restrict__ baseLocal, const int* __restrict__ blockOffset,
    uint4* __restrict__ sortedFeat, int* __restrict__ sortedMeta) {
  int i = blockIdx.x * blockDim.x + threadIdx.x;
  int2 m = kr[i];
  int key = m.x & 0x7fffffff;
  int pos = baseLocal[key] + blockOffset[key >> 10] + m.y;
  const float4* f = (const float4*)(features + (size_t)i * IN_CH);
  float4 f0 = f[0], f1 = f[1], f2 = f[2], f3 = f[3];
  uint4 w0, w1;
  w0.x = pk2(f0.x, f0.y); w0.y = pk2(f0.z, f0.w);
  w0.z = pk2(f1.x, f1.y); w0.w = pk2(f1.z, f1.w);
  w1.x = pk2(f2.x, f2.y); w1.y = pk2(f2.z, f2.w);
  w1.z = pk2(f3.x, f3.y); w1.w = pk2(f3.z, f3.w);
  sortedFeat[(size_t)pos * 2] = w0;
  sortedFeat[(size_t)pos * 2 + 1] = w1;
  int x = key % Ww;
  sortedMeta[pos] = i | (x << 19) | (m.x & (int)0x80000000);
}

// ---- C: fused conv: inline accumulate + MFMA + event-parallel out ----------
// __launch_bounds__(256, 8): request 8 blocks/CU (32 waves) — the kernel is
// latency-bound (all pipes <25%) and was running at only ~2.5 blocks/CU.
__global__ __launch_bounds__(256, 8) void fused_conv_kernel(
    const uint4* __restrict__ sortedFeat, const int* __restrict__ sortedMeta,
    const int* __restrict__ baseLocal, const int* __restrict__ blockOffset,
    const unsigned short* __restrict__ wprep, const float* __restrict__ bias,
    float* __restrict__ out) {
  __shared__ unsigned smem[128 * OPITCH];  // 16896 B (>= 3072 dwords for halo)
  __shared__ int rowRg[TH][2];             // per image row: [start, end) pos

  int blk = blockIdx.x;
  int xt = blk % NXT_TILES;
  int rem = blk / NXT_TILES;
  int yt = rem % NYT_TILES;
  int b = rem / NYT_TILES;
  int x0 = xt * TW, y0 = yt * TH;
  int tid = threadIdx.x;

  if (tid < 12) smem[3060 + tid] = 0;  // zero A-read overrun pad

  // ---- stage 0: per-row event ranges (rows contiguous in sorted order) ----
  int tx = tid & 31, ty = tid >> 5;
  int gxo = x0 + tx;
  int xlast = min(x0 + TW - 1, Ww - 1);
  if (gxo < Ww) {
    int p = (b * Hh + y0 + ty) * Ww + gxo;
    int bo = blockOffset[p >> 10];
    int base = baseLocal[p] + bo;
    if (tx == 0) rowRg[ty][0] = base;
    if (gxo == xlast) {
      int nxt = ((p & 1023) != 1023) ? (baseLocal[p + 1] + bo)
                                     : blockOffset[(p >> 10) + 1];
      rowRg[ty][1] = nxt;
    }
  }

  // ---- stage 1: build normalized bf16 dense halo in LDS ----
  for (int h = tid; h < HALO_PIX; h += 256) {
    int hy = h / HW_, hx = h % HW_;
    int gy = y0 - 1 + hy, gx = x0 - 1 + hx;
    float acc[CIN];
#pragma unroll
    for (int k = 0; k < CIN; k++) acc[k] = 0.0f;
    int c = 0, base = 0;
    if (gy >= 0 && gy < Hh && gx >= 0 && gx < Ww) {
      int p = (b * Hh + gy) * Ww + gx;
      int bo = blockOffset[p >> 10];
      base = baseLocal[p] + bo;
      int nxt = ((p & 1023) != 1023) ? (baseLocal[p + 1] + bo)
                                     : blockOffset[(p >> 10) + 1];
      c = nxt - base;
      for (int j = 0; j < c; j++) {
        int e = sortedMeta[base + j];
        float pol = (float)((unsigned)e >> 31);
        acc[0] += pol;
        acc[1] += 1.0f - pol;
        uint4 w0 = sortedFeat[(size_t)(base + j) * 2];
        uint4 w1 = sortedFeat[(size_t)(base + j) * 2 + 1];
        acc[2] += bf2f((unsigned short)w0.x);  acc[3] += bf2f((unsigned short)(w0.x >> 16));
        acc[4] += bf2f((unsigned short)w0.y);  acc[5] += bf2f((unsigned short)(w0.y >> 16));
        acc[6] += bf2f((unsigned short)w0.z);  acc[7] += bf2f((unsigned short)(w0.z >> 16));
        acc[8] += bf2f((unsigned short)w0.w);  acc[9] += bf2f((unsigned short)(w0.w >> 16));
        acc[10] += bf2f((unsigned short)w1.x); acc[11] += bf2f((unsigned short)(w1.x >> 16));
        acc[12] += bf2f((unsigned short)w1.y); acc[13] += bf2f((unsigned short)(w1.y >> 16));
        acc[14] += bf2f((unsigned short)w1.z); acc[15] += bf2f((unsigned short)(w1.z >> 16));
        acc[16] += bf2f((unsigned short)w1.w); acc[17] += bf2f((unsigned short)(w1.w >> 16));
      }
    }
    float inv = 1.0f / fmaxf((float)c, 1.0f);
    unsigned* row = smem + 9 * h;  // 18 bf16 = 9 dwords
#pragma unroll
    for (int k = 0; k < 9; k++)
      row[k] = pk2(acc[2 * k] * inv, acc[2 * k + 1] * inv);
  }
  __syncthreads();

  // ---- stage 2: MFMA GEMM from LDS halo (ky-outer to cut VGPR) ----
  int wv = tid >> 6, lane = tid & 63;
  int quad = lane >> 4, lrow = lane & 15;

  f32x4 accf[4][2];
#pragma unroll
  for (int i = 0; i < 4; i++)
#pragma unroll
    for (int nt = 0; nt < 2; nt++) accf[i][nt] = (f32x4){0.f, 0.f, 0.f, 0.f};

  const unsigned* hp = smem;
#pragma unroll
  for (int ky = 0; ky < 3; ky++) {
    bf16x8 bfr[2][2];  // [khalf][ntile]
#pragma unroll
    for (int kh = 0; kh < 2; kh++)
#pragma unroll
      for (int nt = 0; nt < 2; nt++) {
        int n = nt * 16 + lrow;
        bfr[kh][nt] = *(const bf16x8*)(wprep + ((ky * 32 + n) << 6) +
                                       kh * 32 + quad * 8);
      }
#pragma unroll
    for (int i = 0; i < 4; i++) {  // m-tiles of this wave
      int t0 = (wv * 4 + i) * 16;
      int ox = (t0 & 31) + lrow;   // A: m = lane&15
      int oy = t0 >> 5;
      int idx0 = ((oy + ky) * HW_ + ox) * CIN;  // even (shorts)
#pragma unroll
      for (int kh = 0; kh < 2; kh++) {
        union { bf16x8 v; unsigned u[4]; } a;
        int ui = (idx0 >> 1) + kh * 16 + quad * 4;
        a.u[0] = hp[ui]; a.u[1] = hp[ui + 1];
        a.u[2] = hp[ui + 2]; a.u[3] = hp[ui + 3];
        accf[i][0] = __builtin_amdgcn_mfma_f32_16x16x32_bf16(
            a.v, bfr[kh][0], accf[i][0], 0, 0, 0);
        accf[i][1] = __builtin_amdgcn_mfma_f32_16x16x32_bf16(
            a.v, bfr[kh][1], accf[i][1], 0, 0, 0);
      }
    }
  }
  __syncthreads();  // halo dead; smem becomes out repack (128 rows x 33)

  // ---- stages 3+4, chunked: repack then EVENT-PARALLEL coalesced writes ----
  float* outsh = (float*)smem;
  float bn0 = bias[lrow], bn1 = bias[16 + lrow];  // D: col = lane&15
#pragma unroll
  for (int ch = 0; ch < 2; ch++) {
#pragma unroll
    for (int ii = 0; ii < 2; ii++) {
      int i = ch * 2 + ii;
      int lidx = ii * 16 + quad * 4;         // local row within chunk [0,32)
      int row = wv * 32 + lidx;
#pragma unroll
      for (int r = 0; r < 4; r++) {
        outsh[(row + r) * OPITCH + lrow] = accf[i][0][r] + bn0;
        outsh[(row + r) * OPITCH + 16 + lrow] = accf[i][1][r] + bn1;
      }
    }
    __syncthreads();
    int lq = tid & 7;        // float4 slot within event
    int grp = tid >> 3;      // event slot (32 groups)
#pragma unroll
    for (int rr = 0; rr < 4; rr++) {
      int ty2 = ch + rr * 2;
      int rS = rowRg[ty2][0], rE = rowRg[ty2][1];
      for (int s = grp; s < rE - rS; s += 32) {
        unsigned meta = (unsigned)sortedMeta[rS + s];
        int ev = meta & 0x7FFFF;
        int lx = (int)((meta >> 19) & 0x1FF) - x0;
        int pid = ty2 * 32 + lx;
        int orow = ((pid >> 6) << 5) + (((pid >> 4) & 1) << 4) + (pid & 15);
        const float* rp = outsh + orow * OPITCH + (lq << 2);
        float4 v = make_float4(rp[0], rp[1], rp[2], rp[3]);
        ((float4*)(out + (size_t)ev * OUT_CH))[lq] = v;
      }
    }
    __syncthreads();
  }
}

extern "C" void kernel_launch(void* const* d_in, const int* in_sizes, int n_in,
                              void* d_out, int out_size, void* d_ws,
                              size_t ws_size, hipStream_t stream) {
  const float* events = (const float*)d_in[0];
  const float* features = (const float*)d_in[1];
  const float* weight = (const float*)d_in[2];
  const float* bias = (const float*)d_in[3];
  const int* offsets = (const int*)d_in[4];
  float* out = (float*)d_out;

  uint4* sortedFeat = (uint4*)d_ws;                        // N_EV * 32B
  int* sortedMeta = (int*)(sortedFeat + (size_t)N_EV * 2); // N_EV
  int2* kr = (int2*)(sortedMeta + N_EV);                   // N_EV * 8B
  int* hist = (int*)(kr + N_EV);                           // NSEG (scan in place)
  int* blockOffset = hist + NSEG;                          // NBLK+1 (pad 1024)
  int* blockSum = blockOffset + 1024;                      // NBLK (pad 1024)
  unsigned short* wprep = (unsigned short*)(blockSum + 1024);  // 6144 ushort

  hipMemsetAsync(hist, 0, (size_t)NSEG * sizeof(int), stream);

  hist_rank_kernel<<<N_EV / 256, 256, 0, stream>>>(events, offsets, hist, kr);
  scan1_kernel<<<NBLK, 256, 0, stream>>>(hist, blockSum);  // in-place
  scan2_weights_kernel<<<2, 1024, 0, stream>>>(blockSum, blockOffset, weight,
                                               wprep);
  scatter_feat_kernel<<<N_EV / 256, 256, 0, stream>>>(
      features, kr, hist, blockOffset, sortedFeat, sortedMeta);
  fused_conv_kernel<<<Bb * NYT_TILES * NXT_TILES, 256, 0, stream>>>(
      sortedFeat, sortedMeta, hist, blockOffset, wprep, bias, out);
}

// Round 12
// 174.499 us; speedup vs baseline: 1.1033x; 1.1033x over previous
//
#include <hip/hip_runtime.h>

#define Hh 240
#define Ww 304
#define IN_CH 16
#define OUT_CH 32
#define Bb 8
#define N_PER 65536
#define N_EV (Bb * N_PER)      // 524288 = 2^19 (event idx fits 19 bits)
#define CIN (IN_CH + 2)        // 18
#define NSEG (Bb * Hh * Ww)    // 583680 = 570 * 1024
#define NBLK 570               // scan blocks of 1024 elems

// fused conv tiling
#define TW 32
#define TH 8
#define HW_ 34                 // TW + 2 halo
#define HH_ 10                 // TH + 2 halo
#define HALO_PIX (HH_ * HW_)   // 340
#define NXT_TILES 10           // ceil(304/32)
#define NYT_TILES 30           // 240/8
#define OPITCH 33              // out repack pitch (f32)

typedef __attribute__((ext_vector_type(8))) short bf16x8;
typedef __attribute__((ext_vector_type(4))) float f32x4;

__device__ __forceinline__ unsigned short f2bf(float x) {
  unsigned u = __float_as_uint(x);
  unsigned r = u + 0x7fffu + ((u >> 16) & 1u);  // RNE
  return (unsigned short)(r >> 16);
}
__device__ __forceinline__ float bf2f(unsigned short b) {
  return __uint_as_float(((unsigned)b) << 16);
}
__device__ __forceinline__ unsigned pk2(float a, float b) {
  return (unsigned)f2bf(a) | ((unsigned)f2bf(b) << 16);
}

// ---- A: histogram + rank per event; key+rank packed as int2 ----------------
__global__ __launch_bounds__(256) void hist_rank_kernel(
    const float* __restrict__ events, const int* __restrict__ offsets,
    int* __restrict__ hist, int2* __restrict__ kr) {
  int i = blockIdx.x * blockDim.x + threadIdx.x;
  float4 ev = ((const float4*)events)[i];
  int yi = (int)rintf(ev.y * (float)Hh);
  yi = min(max(yi, 0), Hh - 1);
  int xi = (int)rintf(ev.x * (float)Ww);
  xi = min(max(xi, 0), Ww - 1);
  int b = 0;
#pragma unroll
  for (int j = 0; j < Bb; j++) b += (offsets[j] <= i) ? 1 : 0;
  int key = (b * Hh + yi) * Ww + xi;
  int pol = (ev.w != 0.0f) ? 1 : 0;
  int rank = atomicAdd(&hist[key], 1);
  kr[i] = make_int2(key | (pol << 31), rank);
}

// ---- S1: per-1024-block exclusive scan IN PLACE + block totals -------------
__global__ __launch_bounds__(256) void scan1_kernel(int* __restrict__ data,
                                                    int* __restrict__ blockSum) {
  __shared__ int lds[256];
  int b = blockIdx.x, t = threadIdx.x;
  int idx = b * 1024 + t * 4;
  int4 v = *(const int4*)(data + idx);
  int s0 = v.x, s1 = s0 + v.y, s2 = s1 + v.z, s3 = s2 + v.w;
  lds[t] = s3;
  __syncthreads();
  int val = s3;
  for (int off = 1; off < 256; off <<= 1) {
    int n = (t >= off) ? lds[t - off] : 0;
    __syncthreads();
    val += n;
    lds[t] = val;
    __syncthreads();
  }
  int excl = val - s3;
  int4 o;
  o.x = excl; o.y = excl + s0; o.z = excl + s1; o.w = excl + s2;
  *(int4*)(data + idx) = o;
  if (t == 255) blockSum[b] = val;
}

// ---- S2 + W merged: block 0 scans 570 totals; block 1 packs weights --------
// wprep [ky][n][64]: kl<54 -> kx=kl/18, ci=kl%18; kl>=54 zero (CIN stride).
__global__ __launch_bounds__(1024) void scan2_weights_kernel(
    const int* __restrict__ blockSum, int* __restrict__ blockOffset,
    const float* __restrict__ weight, unsigned short* __restrict__ wprep) {
  int t = threadIdx.x;
  if (blockIdx.x == 1) {
#pragma unroll
    for (int it = 0; it < 6; it++) {
      int idx = it * 1024 + t;              // < 3*32*64 = 6144
      int ky = idx >> 11;
      int rem = idx & 2047;
      int n = rem >> 6;
      int kl = rem & 63;
      unsigned short v = 0;
      if (kl < 54) {
        int kx = kl / 18, ci = kl - kx * 18;
        v = f2bf(weight[((ky * 3 + kx) * CIN + ci) * OUT_CH + n]);
      }
      wprep[idx] = v;
    }
    return;
  }
  __shared__ int lds[1024];
  int v = (t < NBLK) ? blockSum[t] : 0;
  lds[t] = v;
  __syncthreads();
  int val = v;
  for (int off = 1; off < 1024; off <<= 1) {
    int n = (t >= off) ? lds[t - off] : 0;
    __syncthreads();
    val += n;
    lds[t] = val;
    __syncthreads();
  }
  if (t < NBLK) blockOffset[t] = val - v;
  if (t == 0) blockOffset[NBLK] = lds[1023];  // = N_EV
}

// ---- B: scatter features (bf16, 32B) + meta into sorted order --------------
// sortedMeta[pos] = ev_idx(19b) | x(9b)<<19 | pol<<31 — stage 4 recovers the
// output pixel arithmetically; stage 1 reads pol from bit 31.
__global__ __launch_bounds__(256) void scatter_feat_kernel(
    const float* __restrict__ features, const int2* __restrict__ kr,
    const int* __restrict__ baseLocal, const int* __restrict__ blockOffset,
    uint4* __restrict__ sortedFeat, int* __restrict__ sortedMeta) {
  int i = blockIdx.x * blockDim.x + threadIdx.x;
  int2 m = kr[i];
  int key = m.x & 0x7fffffff;
  int pos = baseLocal[key] + blockOffset[key >> 10] + m.y;
  const float4* f = (const float4*)(features + (size_t)i * IN_CH);
  float4 f0 = f[0], f1 = f[1], f2 = f[2], f3 = f[3];
  uint4 w0, w1;
  w0.x = pk2(f0.x, f0.y); w0.y = pk2(f0.z, f0.w);
  w0.z = pk2(f1.x, f1.y); w0.w = pk2(f1.z, f1.w);
  w1.x = pk2(f2.x, f2.y); w1.y = pk2(f2.z, f2.w);
  w1.z = pk2(f3.x, f3.y); w1.w = pk2(f3.z, f3.w);
  sortedFeat[(size_t)pos * 2] = w0;
  sortedFeat[(size_t)pos * 2 + 1] = w1;
  int x = key % Ww;
  sortedMeta[pos] = i | (x << 19) | (m.x & (int)0x80000000);
}

// ---- C: fused conv: inline accumulate + MFMA + event-parallel out ----------
// __launch_bounds__(256, 5): request 5 blocks/CU. VGPR cap = 512/5 ~= 102,
// above the kernel's natural allocation -> no spill (R11's (256,8) capped at
// 64 and spilled: WRITE_SIZE 65.5->104 MB). Spill detector: WRITE_SIZE must
// stay 65536 KB and VGPR_Count ~52.
__global__ __launch_bounds__(256, 5) void fused_conv_kernel(
    const uint4* __restrict__ sortedFeat, const int* __restrict__ sortedMeta,
    const int* __restrict__ baseLocal, const int* __restrict__ blockOffset,
    const unsigned short* __restrict__ wprep, const float* __restrict__ bias,
    float* __restrict__ out) {
  __shared__ unsigned smem[128 * OPITCH];  // 16896 B (>= 3072 dwords for halo)
  __shared__ int rowRg[TH][2];             // per image row: [start, end) pos

  int blk = blockIdx.x;
  int xt = blk % NXT_TILES;
  int rem = blk / NXT_TILES;
  int yt = rem % NYT_TILES;
  int b = rem / NYT_TILES;
  int x0 = xt * TW, y0 = yt * TH;
  int tid = threadIdx.x;

  if (tid < 12) smem[3060 + tid] = 0;  // zero A-read overrun pad

  // ---- stage 0: per-row event ranges (rows contiguous in sorted order) ----
  int tx = tid & 31, ty = tid >> 5;
  int gxo = x0 + tx;
  int xlast = min(x0 + TW - 1, Ww - 1);
  if (gxo < Ww) {
    int p = (b * Hh + y0 + ty) * Ww + gxo;
    int bo = blockOffset[p >> 10];
    int base = baseLocal[p] + bo;
    if (tx == 0) rowRg[ty][0] = base;
    if (gxo == xlast) {
      int nxt = ((p & 1023) != 1023) ? (baseLocal[p + 1] + bo)
                                     : blockOffset[(p >> 10) + 1];
      rowRg[ty][1] = nxt;
    }
  }

  // ---- stage 1: build normalized bf16 dense halo in LDS ----
  for (int h = tid; h < HALO_PIX; h += 256) {
    int hy = h / HW_, hx = h % HW_;
    int gy = y0 - 1 + hy, gx = x0 - 1 + hx;
    float acc[CIN];
#pragma unroll
    for (int k = 0; k < CIN; k++) acc[k] = 0.0f;
    int c = 0, base = 0;
    if (gy >= 0 && gy < Hh && gx >= 0 && gx < Ww) {
      int p = (b * Hh + gy) * Ww + gx;
      int bo = blockOffset[p >> 10];
      base = baseLocal[p] + bo;
      int nxt = ((p & 1023) != 1023) ? (baseLocal[p + 1] + bo)
                                     : blockOffset[(p >> 10) + 1];
      c = nxt - base;
      for (int j = 0; j < c; j++) {
        int e = sortedMeta[base + j];
        float pol = (float)((unsigned)e >> 31);
        acc[0] += pol;
        acc[1] += 1.0f - pol;
        uint4 w0 = sortedFeat[(size_t)(base + j) * 2];
        uint4 w1 = sortedFeat[(size_t)(base + j) * 2 + 1];
        acc[2] += bf2f((unsigned short)w0.x);  acc[3] += bf2f((unsigned short)(w0.x >> 16));
        acc[4] += bf2f((unsigned short)w0.y);  acc[5] += bf2f((unsigned short)(w0.y >> 16));
        acc[6] += bf2f((unsigned short)w0.z);  acc[7] += bf2f((unsigned short)(w0.z >> 16));
        acc[8] += bf2f((unsigned short)w0.w);  acc[9] += bf2f((unsigned short)(w0.w >> 16));
        acc[10] += bf2f((unsigned short)w1.x); acc[11] += bf2f((unsigned short)(w1.x >> 16));
        acc[12] += bf2f((unsigned short)w1.y); acc[13] += bf2f((unsigned short)(w1.y >> 16));
        acc[14] += bf2f((unsigned short)w1.z); acc[15] += bf2f((unsigned short)(w1.z >> 16));
        acc[16] += bf2f((unsigned short)w1.w); acc[17] += bf2f((unsigned short)(w1.w >> 16));
      }
    }
    float inv = 1.0f / fmaxf((float)c, 1.0f);
    unsigned* row = smem + 9 * h;  // 18 bf16 = 9 dwords
#pragma unroll
    for (int k = 0; k < 9; k++)
      row[k] = pk2(acc[2 * k] * inv, acc[2 * k + 1] * inv);
  }
  __syncthreads();

  // ---- stage 2: MFMA GEMM from LDS halo (ky-outer to cut VGPR) ----
  int wv = tid >> 6, lane = tid & 63;
  int quad = lane >> 4, lrow = lane & 15;

  f32x4 accf[4][2];
#pragma unroll
  for (int i = 0; i < 4; i++)
#pragma unroll
    for (int nt = 0; nt < 2; nt++) accf[i][nt] = (f32x4){0.f, 0.f, 0.f, 0.f};

  const unsigned* hp = smem;
#pragma unroll
  for (int ky = 0; ky < 3; ky++) {
    bf16x8 bfr[2][2];  // [khalf][ntile]
#pragma unroll
    for (int kh = 0; kh < 2; kh++)
#pragma unroll
      for (int nt = 0; nt < 2; nt++) {
        int n = nt * 16 + lrow;
        bfr[kh][nt] = *(const bf16x8*)(wprep + ((ky * 32 + n) << 6) +
                                       kh * 32 + quad * 8);
      }
#pragma unroll
    for (int i = 0; i < 4; i++) {  // m-tiles of this wave
      int t0 = (wv * 4 + i) * 16;
      int ox = (t0 & 31) + lrow;   // A: m = lane&15
      int oy = t0 >> 5;
      int idx0 = ((oy + ky) * HW_ + ox) * CIN;  // even (shorts)
#pragma unroll
      for (int kh = 0; kh < 2; kh++) {
        union { bf16x8 v; unsigned u[4]; } a;
        int ui = (idx0 >> 1) + kh * 16 + quad * 4;
        a.u[0] = hp[ui]; a.u[1] = hp[ui + 1];
        a.u[2] = hp[ui + 2]; a.u[3] = hp[ui + 3];
        accf[i][0] = __builtin_amdgcn_mfma_f32_16x16x32_bf16(
            a.v, bfr[kh][0], accf[i][0], 0, 0, 0);
        accf[i][1] = __builtin_amdgcn_mfma_f32_16x16x32_bf16(
            a.v, bfr[kh][1], accf[i][1], 0, 0, 0);
      }
    }
  }
  __syncthreads();  // halo dead; smem becomes out repack (128 rows x 33)

  // ---- stages 3+4, chunked: repack then EVENT-PARALLEL coalesced writes ----
  float* outsh = (float*)smem;
  float bn0 = bias[lrow], bn1 = bias[16 + lrow];  // D: col = lane&15
#pragma unroll
  for (int ch = 0; ch < 2; ch++) {
#pragma unroll
    for (int ii = 0; ii < 2; ii++) {
      int i = ch * 2 + ii;
      int lidx = ii * 16 + quad * 4;         // local row within chunk [0,32)
      int row = wv * 32 + lidx;
#pragma unroll
      for (int r = 0; r < 4; r++) {
        outsh[(row + r) * OPITCH + lrow] = accf[i][0][r] + bn0;
        outsh[(row + r) * OPITCH + 16 + lrow] = accf[i][1][r] + bn1;
      }
    }
    __syncthreads();
    int lq = tid & 7;        // float4 slot within event
    int grp = tid >> 3;      // event slot (32 groups)
#pragma unroll
    for (int rr = 0; rr < 4; rr++) {
      int ty2 = ch + rr * 2;
      int rS = rowRg[ty2][0], rE = rowRg[ty2][1];
      for (int s = grp; s < rE - rS; s += 32) {
        unsigned meta = (unsigned)sortedMeta[rS + s];
        int ev = meta & 0x7FFFF;
        int lx = (int)((meta >> 19) & 0x1FF) - x0;
        int pid = ty2 * 32 + lx;
        int orow = ((pid >> 6) << 5) + (((pid >> 4) & 1) << 4) + (pid & 15);
        const float* rp = outsh + orow * OPITCH + (lq << 2);
        float4 v = make_float4(rp[0], rp[1], rp[2], rp[3]);
        ((float4*)(out + (size_t)ev * OUT_CH))[lq] = v;
      }
    }
    __syncthreads();
  }
}

extern "C" void kernel_launch(void* const* d_in, const int* in_sizes, int n_in,
                              void* d_out, int out_size, void* d_ws,
                              size_t ws_size, hipStream_t stream) {
  const float* events = (const float*)d_in[0];
  const float* features = (const float*)d_in[1];
  const float* weight = (const float*)d_in[2];
  const float* bias = (const float*)d_in[3];
  const int* offsets = (const int*)d_in[4];
  float* out = (float*)d_out;

  uint4* sortedFeat = (uint4*)d_ws;                        // N_EV * 32B
  int* sortedMeta = (int*)(sortedFeat + (size_t)N_EV * 2); // N_EV
  int2* kr = (int2*)(sortedMeta + N_EV);                   // N_EV * 8B
  int* hist = (int*)(kr + N_EV);                           // NSEG (scan in place)
  int* blockOffset = hist + NSEG;                          // NBLK+1 (pad 1024)
  int* blockSum = blockOffset + 1024;                      // NBLK (pad 1024)
  unsigned short* wprep = (unsigned short*)(blockSum + 1024);  // 6144 ushort

  hipMemsetAsync(hist, 0, (size_t)NSEG * sizeof(int), stream);

  hist_rank_kernel<<<N_EV / 256, 256, 0, stream>>>(events, offsets, hist, kr);
  scan1_kernel<<<NBLK, 256, 0, stream>>>(hist, blockSum);  // in-place
  scan2_weights_kernel<<<2, 1024, 0, stream>>>(blockSum, blockOffset, weight,
                                               wprep);
  scatter_feat_kernel<<<N_EV / 256, 256, 0, stream>>>(
      features, kr, hist, blockOffset, sortedFeat, sortedMeta);
  fused_conv_kernel<<<Bb * NYT_TILES * NXT_TILES, 256, 0, stream>>>(
      sortedFeat, sortedMeta, hist, blockOffset, wprep, bias, out);
}